// Round 3
// baseline (613.160 us; speedup 1.0000x reference)
//
#include <hip/hip_runtime.h>

typedef __bf16 bf16_t;
typedef __attribute__((ext_vector_type(8))) __bf16 bf16x8;
typedef __attribute__((ext_vector_type(4))) float f32x4;
typedef __attribute__((ext_vector_type(8))) unsigned short u16x8;
typedef __attribute__((ext_vector_type(4))) unsigned short u16x4;

#define LBS 40    // B-slab / A-chunk LDS row stride in shorts (16B aligned)
#define LHS 520   // H LDS row stride in shorts (16B aligned)

// ---------------- dtype detect: 1 = bf16 inputs, 0 = fp32 inputs.
// comp_table row 0 is all zeros. u16 words [256,272):
//   bf16-world: row 1 cols 0..15 = N(0,0.02) bf16 -> exp field in [80,126]
//   fp32-world: fp32 elements 128..135 = row 0 zeros -> all bits 0 -> exp field 0
__global__ void detect_dtype(const unsigned short* __restrict__ ct, int* __restrict__ flag) {
    if (threadIdx.x == 0 && blockIdx.x == 0) {
        int ok = 1;
        for (int i = 0; i < 16; i++) {
            int e = (ct[256 + i] >> 7) & 0xFF;
            ok &= (e >= 80 && e <= 126) ? 1 : 0;
        }
        *flag = ok;
    }
}

// ---------------- scan: partition rows into ternary/binary lists; build node->slot inverse
__global__ void scan_rows(const int* __restrict__ lvl2, const int* __restrict__ lvl1,
                          const int* __restrict__ lvl0, const int* __restrict__ third,
                          int* __restrict__ lists, int* __restrict__ cnts, int* __restrict__ inv) {
    int r = blockIdx.x * 256 + threadIdx.x;
    if (r >= 28672) return;
    int slot, lr, base_t, base_b;
    const int* lvl;
    if (r < 16384)      { slot = 0; lr = r;         lvl = lvl2; base_t = 0;     base_b = 16384; }
    else if (r < 24576) { slot = 1; lr = r - 16384; lvl = lvl1; base_t = 32768; base_b = 40960; }
    else                { slot = 2; lr = r - 24576; lvl = lvl0; base_t = 49152; base_b = 53248; }
    int node = lvl[lr];
    int tern = third[node] >= 0 ? 1 : 0;
    int p = atomicAdd(&cnts[slot * 2 + tern], 1);
    lists[(tern ? base_t : base_b) + p] = lr;
    if (slot == 0)      inv[node] = lr;          // lvl2 outputs -> slots [0,16384)
    else if (slot == 1) inv[node] = 16384 + lr;  // lvl1 outputs -> slots [16384,24576)
}

// ---------------- op_table -> bf16 copy/convert (always bf16 in ws)
__global__ void conv_op(const void* __restrict__ op, bf16_t* __restrict__ opb,
                        const int* __restrict__ flagp) {
    int i = blockIdx.x * 256 + threadIdx.x;   // 4096 = 16*256
    opb[i] = (*flagp) ? ((const bf16_t*)op)[i] : (bf16_t)((const float*)op)[i];
}

// ---------------- pack weights [K][N] -> [K/32][N][32] bf16 (B-fragment friendly)
__global__ void pack_w(const void* __restrict__ src, bf16_t* __restrict__ dst,
                       int KN, int Nmask, int Nshift, const int* __restrict__ flagp) {
    int e = blockIdx.x * 256 + threadIdx.x;
    if (e >= KN) return;
    bf16_t v = (*flagp) ? ((const bf16_t*)src)[e] : (bf16_t)((const float*)src)[e];
    int n = e & Nmask, k = e >> Nshift;
    dst[(size_t)((((k >> 5) << Nshift) + n) * 32 + (k & 31))] = v;
}

__device__ __forceinline__ void load8f(const bf16_t* ne2, const void* ct, int isbf,
                                       int invn, int cidn, int q, float* o) {
    if (invn >= 0) {
        bf16x8 v = *(const bf16x8*)(ne2 + (size_t)invn * 256 + q);
        for (int z = 0; z < 8; z++) o[z] = (float)v[z];
    } else if (isbf) {
        bf16x8 v = *(const bf16x8*)((const bf16_t*)ct + (size_t)cidn * 256 + q);
        for (int z = 0; z < 8; z++) o[z] = (float)v[z];
    } else {
        const float* fp = (const float*)ct + (size_t)cidn * 256 + q;
        f32x4 a = *(const f32x4*)fp, b = *(const f32x4*)(fp + 4);
        for (int z = 0; z < 4; z++) { o[z] = a[z]; o[z + 4] = b[z]; }
    }
}

__device__ __forceinline__ float ldparam(const void* p, int i, int isbf) {
    return isbf ? (float)((const bf16_t*)p)[i] : ((const float*)p)[i];
}

// ---------------- fused level kernel: gather -> GEMM1 -> gelu -> GEMM2 -> residual+LN -> scatter
__global__ __launch_bounds__(256, 2) void fused_level(
    const int* __restrict__ list, const int* __restrict__ cntp,
    const int* __restrict__ lvl_idx,
    const int* __restrict__ op_ids, const int* __restrict__ lch,
    const int* __restrict__ rch, const int* __restrict__ tch,
    bf16_t* __restrict__ ne2, const bf16_t* __restrict__ opb,
    const void* __restrict__ ct, const int* __restrict__ cid,
    const int* __restrict__ inv, const int* __restrict__ flagp,
    const bf16_t* __restrict__ W1p, const void* __restrict__ b1,
    const bf16_t* __restrict__ W2p, const void* __restrict__ b2,
    const void* __restrict__ gma, const void* __restrict__ bta,
    int K1c, int tern, int slotBase, void* __restrict__ out)
{
    __shared__ __align__(16) unsigned short reg1[20480]; // B1 slab [512][40] | H [32][520] | R float[32][260]
    __shared__ __align__(16) unsigned short regA[1280];  // A chunk [32][40]  | LN partials
    __shared__ __align__(16) unsigned short reg2[10240]; // B2 slab [256][40]

    const int tid = threadIdx.x;
    const int w = tid >> 6, lane = tid & 63, cc = lane & 15, qq = lane >> 4;
    const int cnt = *cntp;
    const int base = blockIdx.x * 32;
    if (base >= cnt) return;
    const int act = min(32, cnt - base);
    const int isbf = *flagp;

    // staging identity: thread covers row ms, col-group gs
    const int ms = tid >> 3, gs = tid & 7;
    const int rowS = list[base + min(ms, act - 1)];
    const int nodeS = lvl_idx[rowS];
    const int opS = op_ids[nodeS];
    const int lS = lch[nodeS], rS = rch[nodeS];
    const int tS = tern ? tch[nodeS] : lS;
    int sInv[3], sCid[3];
    {
        int sn[3] = {lS, rS, tS};
        for (int s = 0; s < 3; s++) {
            sInv[s] = inv[sn[s]];
            sCid[s] = sInv[s] < 0 ? cid[sn[s]] : 0;
        }
    }

    // per-lane bias / gamma / beta (cols owned by this lane)
    float b1f[8];
    for (int j = 0; j < 8; j++) b1f[j] = ldparam(b1, (w + 4 * j) * 16 + cc, isbf);
    float b2f[4], gf[4], btf[4];
    for (int j = 0; j < 4; j++) {
        int col = (w + 4 * j) * 16 + cc;
        b2f[j] = ldparam(b2, col, isbf);
        gf[j] = ldparam(gma, col, isbf);
        btf[j] = ldparam(bta, col, isbf);
    }

    const f32x4 zf = {0.f, 0.f, 0.f, 0.f};
    f32x4 acc1[2][8];
    for (int m = 0; m < 2; m++) for (int j = 0; j < 8; j++) acc1[m][j] = zf;

    // ---------- GEMM1: [32 x K1] @ [K1 x 512]
    for (int kc = 0; kc < K1c; kc++) {
        __syncthreads();
        { // A chunk gather: 32 rows x 32 cols of concat(op,le,re[,te])
            int colg = kc * 32 + gs * 4;
            int piece = colg >> 8, po = colg & 255;
            u16x4 hv;
            if (piece == 0) {
                hv = *(const u16x4*)((const unsigned short*)opb + opS * 256 + po);
            } else {
                int s = piece - 1;
                if (sInv[s] >= 0) {
                    hv = *(const u16x4*)((const unsigned short*)ne2 + (size_t)sInv[s] * 256 + po);
                } else if (isbf) {
                    hv = *(const u16x4*)((const unsigned short*)ct + (size_t)sCid[s] * 256 + po);
                } else {
                    f32x4 fv = *(const f32x4*)((const float*)ct + (size_t)sCid[s] * 256 + po);
                    bf16_t tmp[4];
                    for (int z = 0; z < 4; z++) tmp[z] = (bf16_t)fv[z];
                    hv = *(u16x4*)tmp;
                }
            }
            *(u16x4*)(regA + ms * LBS + gs * 4) = hv;
        }
        // B slab: 512n x 32k shorts = 2048 16B chunks, 8 per thread
        for (int i = 0; i < 8; i++) {
            int idx = i * 256 + tid;
            int n = idx >> 2, g = idx & 3;
            u16x8 v = *(const u16x8*)((const unsigned short*)W1p + ((size_t)kc * 512 + n) * 32 + g * 8);
            *(u16x8*)(reg1 + n * LBS + g * 8) = v;
        }
        __syncthreads();
        bf16x8 af[2];
        for (int m = 0; m < 2; m++)
            af[m] = *(const bf16x8*)((const bf16_t*)regA + (m * 16 + cc) * LBS + qq * 8);
        for (int j = 0; j < 8; j++) {
            bf16x8 bfv = *(const bf16x8*)((const bf16_t*)reg1 + ((w + 4 * j) * 16 + cc) * LBS + qq * 8);
            for (int m = 0; m < 2; m++)
                acc1[m][j] = __builtin_amdgcn_mfma_f32_16x16x32_bf16(af[m], bfv, acc1[m][j], 0, 0, 0);
        }
    }
    __syncthreads();

    // ---------- bias + exact GELU -> H in LDS [32][512] (stride 520)
    {
        bf16_t* Hl = (bf16_t*)reg1;
        for (int m = 0; m < 2; m++) for (int j = 0; j < 8; j++) {
            int col = (w + 4 * j) * 16 + cc;
            for (int r = 0; r < 4; r++) {
                float v = acc1[m][j][r] + b1f[j];
                float h = 0.5f * v * (1.0f + erff(v * 0.70710678118654752f));
                Hl[(m * 16 + qq * 4 + r) * LHS + col] = (bf16_t)h;
            }
        }
    }
    __syncthreads();

    // ---------- GEMM2: [32 x 512] @ [512 x 256]
    f32x4 acc2[2][4];
    for (int m = 0; m < 2; m++) for (int j = 0; j < 4; j++) acc2[m][j] = zf;
    for (int kc = 0; kc < 16; kc++) {
        if (kc) __syncthreads();
        for (int i = 0; i < 4; i++) {
            int idx = i * 256 + tid;
            int n = idx >> 2, g = idx & 3;
            u16x8 v = *(const u16x8*)((const unsigned short*)W2p + ((size_t)kc * 256 + n) * 32 + g * 8);
            *(u16x8*)(reg2 + n * LBS + g * 8) = v;
        }
        __syncthreads();
        bf16x8 af[2];
        for (int m = 0; m < 2; m++)
            af[m] = *(const bf16x8*)((const bf16_t*)reg1 + (m * 16 + cc) * LHS + kc * 32 + qq * 8);
        for (int j = 0; j < 4; j++) {
            bf16x8 bfv = *(const bf16x8*)((const bf16_t*)reg2 + ((w + 4 * j) * 16 + cc) * LBS + qq * 8);
            for (int m = 0; m < 2; m++)
                acc2[m][j] = __builtin_amdgcn_mfma_f32_16x16x32_bf16(af[m], bfv, acc2[m][j], 0, 0, 0);
        }
    }
    __syncthreads();

    // ---------- residual gather -> reg1 as float[32][260]
    {
        float* Rf = (float*)reg1;
        int colb = gs * 32;
        for (int i = 0; i < 4; i++) {
            int q = colb + i * 8;
            float lv[8], rv[8], tv[8];
            load8f(ne2, ct, isbf, sInv[0], sCid[0], q, lv);
            load8f(ne2, ct, isbf, sInv[1], sCid[1], q, rv);
            if (tern) load8f(ne2, ct, isbf, sInv[2], sCid[2], q, tv);
            f32x4 s0, s1;
            if (tern) {
                for (int z = 0; z < 4; z++) {
                    s0[z] = (lv[z] + rv[z] + tv[z]) * (1.0f / 3.0f);
                    s1[z] = (lv[z + 4] + rv[z + 4] + tv[z + 4]) * (1.0f / 3.0f);
                }
            } else {
                for (int z = 0; z < 4; z++) {
                    s0[z] = lv[z] + rv[z];
                    s1[z] = lv[z + 4] + rv[z + 4];
                }
            }
            *(f32x4*)(Rf + ms * 260 + q) = s0;
            *(f32x4*)(Rf + ms * 260 + q + 4) = s1;
        }
    }
    __syncthreads();

    // ---------- x = gemm2 + b2 + R ; LayerNorm over 256 cols per row
    float* partS = (float*)regA;      // [4][32]
    float* partQ = partS + 128;       // [4][32]
    float* muA   = partQ + 128;       // [32]
    float* rsA   = muA + 32;          // [32]
    const float* Rf = (const float*)reg1;

    for (int m = 0; m < 2; m++) for (int r = 0; r < 4; r++) {
        int row = m * 16 + qq * 4 + r;
        float ps = 0.f, pq = 0.f;
        for (int j = 0; j < 4; j++) {
            int col = (w + 4 * j) * 16 + cc;
            float x = acc2[m][j][r] + b2f[j] + Rf[row * 260 + col];
            acc2[m][j][r] = x;
            ps += x; pq += x * x;
        }
        for (int d = 1; d < 16; d <<= 1) {
            ps += __shfl_xor(ps, d, 64);
            pq += __shfl_xor(pq, d, 64);
        }
        if (cc == 0) { partS[w * 32 + row] = ps; partQ[w * 32 + row] = pq; }
    }
    __syncthreads();
    if (tid < 32) {
        float s  = partS[tid] + partS[32 + tid] + partS[64 + tid] + partS[96 + tid];
        float sq = partQ[tid] + partQ[32 + tid] + partQ[64 + tid] + partQ[96 + tid];
        float mu = s * (1.0f / 256.0f);
        float var = sq * (1.0f / 256.0f) - mu * mu;
        muA[tid] = mu;
        rsA[tid] = rsqrtf(fmaxf(var, 0.0f) + 1e-5f);
    }
    __syncthreads();

    for (int m = 0; m < 2; m++) for (int r = 0; r < 4; r++) {
        int row = m * 16 + qq * 4 + r;
        if (row >= act) continue;
        float mu = muA[row], rs = rsA[row];
        int lr2 = list[base + row];
        for (int j = 0; j < 4; j++) {
            int col = (w + 4 * j) * 16 + cc;
            float y = (acc2[m][j][r] - mu) * rs * gf[j] + btf[j];
            if (out) {
                if (isbf) ((bf16_t*)out)[(size_t)lr2 * 256 + col] = (bf16_t)y;
                else      ((float*)out)[(size_t)lr2 * 256 + col] = y;
            } else {
                ne2[(size_t)(slotBase + lr2) * 256 + col] = (bf16_t)y;
            }
        }
    }
}

extern "C" void kernel_launch(void* const* d_in, const int* in_sizes, int n_in,
                              void* d_out, int out_size, void* d_ws, size_t ws_size,
                              hipStream_t stream) {
    const int* cid    = (const int*)d_in[0];
    const int* opids  = (const int*)d_in[1];
    const int* lch    = (const int*)d_in[2];
    const int* rch    = (const int*)d_in[3];
    const int* tch    = (const int*)d_in[4];
    const int* lvl2   = (const int*)d_in[5];
    const int* lvl1   = (const int*)d_in[6];
    const int* lvl0   = (const int*)d_in[7];
    const void* comp_table = d_in[8];
    const void* op_table   = d_in[9];
    const void* W1b = d_in[10];
    const void* b1b = d_in[11];
    const void* W2b = d_in[12];
    const void* b2b = d_in[13];
    const void* W1t = d_in[14];
    const void* b1t = d_in[15];
    const void* W2t = d_in[16];
    const void* b2t = d_in[17];
    const void* gma = d_in[18];
    const void* bta = d_in[19];

    char* wsp = (char*)d_ws;
    bf16_t* ne2  = (bf16_t*)wsp;                 size_t off = 12582912; // 24576*256*2
    bf16_t* opb  = (bf16_t*)(wsp + off);         off += 8192;           // 16*256*2
    bf16_t* W1bp = (bf16_t*)(wsp + off);         off += 786432;         // 768*512*2
    bf16_t* W1tp = (bf16_t*)(wsp + off);         off += 1048576;        // 1024*512*2
    bf16_t* W2bp = (bf16_t*)(wsp + off);         off += 262144;         // 512*256*2
    bf16_t* W2tp = (bf16_t*)(wsp + off);         off += 262144;
    int* inv   = (int*)(wsp + off);              off += 262144;         // 65536*4
    int* lists = (int*)(wsp + off);              off += 229376;         // 57344*4
    int* cnts  = (int*)(wsp + off);              off += 64;             // total ~15.4 MB
    int* flag  = cnts + 8;

    hipMemsetAsync(cnts, 0, 64, stream);
    hipMemsetAsync(inv, 0xFF, 262144, stream);
    detect_dtype<<<1, 64, 0, stream>>>((const unsigned short*)comp_table, flag);
    scan_rows<<<112, 256, 0, stream>>>(lvl2, lvl1, lvl0, tch, lists, cnts, inv);
    conv_op<<<16, 256, 0, stream>>>(op_table, opb, flag);
    pack_w<<<1536, 256, 0, stream>>>(W1b, W1bp, 393216, 511, 9, flag);
    pack_w<<<2048, 256, 0, stream>>>(W1t, W1tp, 524288, 511, 9, flag);
    pack_w<<<512, 256, 0, stream>>>(W2b, W2bp, 131072, 255, 8, flag);
    pack_w<<<512, 256, 0, stream>>>(W2t, W2tp, 131072, 255, 8, flag);

    // level 2 (slot 0): ternary list @0 (cnt[1]), binary list @16384 (cnt[0]) -> slots base 0
    fused_level<<<512, 256, 0, stream>>>(lists + 0, cnts + 1, lvl2, opids, lch, rch, tch,
        ne2, opb, comp_table, cid, inv, flag, W1tp, b1t, W2tp, b2t, gma, bta, 32, 1, 0, nullptr);
    fused_level<<<512, 256, 0, stream>>>(lists + 16384, cnts + 0, lvl2, opids, lch, rch, tch,
        ne2, opb, comp_table, cid, inv, flag, W1bp, b1b, W2bp, b2b, gma, bta, 24, 0, 0, nullptr);
    // level 1 (slot 1): tern @32768 (cnt[3]), bin @40960 (cnt[2]) -> slots base 16384
    fused_level<<<256, 256, 0, stream>>>(lists + 32768, cnts + 3, lvl1, opids, lch, rch, tch,
        ne2, opb, comp_table, cid, inv, flag, W1tp, b1t, W2tp, b2t, gma, bta, 32, 1, 16384, nullptr);
    fused_level<<<256, 256, 0, stream>>>(lists + 40960, cnts + 2, lvl1, opids, lch, rch, tch,
        ne2, opb, comp_table, cid, inv, flag, W1bp, b1b, W2bp, b2b, gma, bta, 24, 0, 16384, nullptr);
    // level 0 (slot 2): tern @49152 (cnt[5]), bin @53248 (cnt[4]) -> write d_out
    fused_level<<<128, 256, 0, stream>>>(lists + 49152, cnts + 5, lvl0, opids, lch, rch, tch,
        ne2, opb, comp_table, cid, inv, flag, W1tp, b1t, W2tp, b2t, gma, bta, 32, 1, 0, d_out);
    fused_level<<<128, 256, 0, stream>>>(lists + 53248, cnts + 4, lvl0, opids, lch, rch, tch,
        ne2, opb, comp_table, cid, inv, flag, W1bp, b1b, W2bp, b2b, gma, bta, 24, 0, 0, d_out);
}

// Round 4
// 289.785 us; speedup vs baseline: 2.1159x; 2.1159x over previous
//
#include <hip/hip_runtime.h>

typedef __bf16 bf16_t;
typedef __attribute__((ext_vector_type(8))) __bf16 bf16x8;
typedef __attribute__((ext_vector_type(4))) float f32x4;
typedef __attribute__((ext_vector_type(8))) unsigned short u16x8;
typedef __attribute__((ext_vector_type(4))) unsigned short u16x4;

#define LBS 40    // B-slab / A-chunk LDS row stride in shorts (16B aligned)
#define LHS 520   // H LDS row stride in shorts (16B aligned)

// ---------------- dtype detect: 1 = bf16 inputs, 0 = fp32 inputs.
__global__ void detect_dtype(const unsigned short* __restrict__ ct, int* __restrict__ flag) {
    if (threadIdx.x == 0 && blockIdx.x == 0) {
        int ok = 1;
        for (int i = 0; i < 16; i++) {
            int e = (ct[256 + i] >> 7) & 0xFF;
            ok &= (e >= 80 && e <= 126) ? 1 : 0;
        }
        *flag = ok;
    }
}

// ---------------- scan: wave-aggregated partition (1 atomic per wave per bucket)
// boundaries 16384/24576/28672 are multiples of 64 -> slot is wave-uniform
__global__ void scan_rows(const int* __restrict__ lvl2, const int* __restrict__ lvl1,
                          const int* __restrict__ lvl0, const int* __restrict__ third,
                          int* __restrict__ lists, int* __restrict__ cnts, int* __restrict__ inv) {
    int r = blockIdx.x * 256 + threadIdx.x;   // grid covers exactly 28672
    int slot, lr, base_t, base_b;
    const int* lvl;
    if (r < 16384)      { slot = 0; lr = r;         lvl = lvl2; base_t = 0;     base_b = 16384; }
    else if (r < 24576) { slot = 1; lr = r - 16384; lvl = lvl1; base_t = 32768; base_b = 40960; }
    else                { slot = 2; lr = r - 24576; lvl = lvl0; base_t = 49152; base_b = 53248; }
    int node = lvl[lr];
    int tern = third[node] >= 0 ? 1 : 0;
    if (slot == 0)      inv[node] = lr;          // lvl2 outputs -> slots [0,16384)
    else if (slot == 1) inv[node] = 16384 + lr;  // lvl1 outputs -> slots [16384,24576)

    unsigned long long bt = __ballot(tern);
    unsigned long long bb = __ballot(!tern);
    int lane = threadIdx.x & 63;
    unsigned long long ltm = (1ull << lane) - 1ull;
    int post = __popcll(bt & ltm), posb = __popcll(bb & ltm);
    int baseT = 0, baseB = 0;
    if (lane == 0) {
        baseT = atomicAdd(&cnts[slot * 2 + 1], __popcll(bt));
        baseB = atomicAdd(&cnts[slot * 2 + 0], __popcll(bb));
    }
    baseT = __shfl(baseT, 0, 64);
    baseB = __shfl(baseB, 0, 64);
    lists[tern ? (base_t + baseT + post) : (base_b + baseB + posb)] = lr;
}

// ---------------- op_table -> bf16 copy/convert (always bf16 in ws)
__global__ void conv_op(const void* __restrict__ op, bf16_t* __restrict__ opb,
                        const int* __restrict__ flagp) {
    int i = blockIdx.x * 256 + threadIdx.x;   // 4096 = 16*256
    opb[i] = (*flagp) ? ((const bf16_t*)op)[i] : (bf16_t)((const float*)op)[i];
}

// ---------------- pack weights [K][N] -> [K/32][N][32] bf16 (B-fragment friendly)
__global__ void pack_w(const void* __restrict__ src, bf16_t* __restrict__ dst,
                       int KN, int Nmask, int Nshift, const int* __restrict__ flagp) {
    int e = blockIdx.x * 256 + threadIdx.x;
    if (e >= KN) return;
    bf16_t v = (*flagp) ? ((const bf16_t*)src)[e] : (bf16_t)((const float*)src)[e];
    int n = e & Nmask, k = e >> Nshift;
    dst[(size_t)((((k >> 5) << Nshift) + n) * 32 + (k & 31))] = v;
}

__device__ __forceinline__ void load8f(const bf16_t* ne2, const void* ct, int isbf,
                                       int invn, int cidn, int q, float* o) {
    if (invn >= 0) {
        bf16x8 v = *(const bf16x8*)(ne2 + (size_t)invn * 256 + q);
        for (int z = 0; z < 8; z++) o[z] = (float)v[z];
    } else if (isbf) {
        bf16x8 v = *(const bf16x8*)((const bf16_t*)ct + (size_t)cidn * 256 + q);
        for (int z = 0; z < 8; z++) o[z] = (float)v[z];
    } else {
        const float* fp = (const float*)ct + (size_t)cidn * 256 + q;
        f32x4 a = *(const f32x4*)fp, b = *(const f32x4*)(fp + 4);
        for (int z = 0; z < 4; z++) { o[z] = a[z]; o[z + 4] = b[z]; }
    }
}

__device__ __forceinline__ float ldparam(const void* p, int i, int isbf) {
    return isbf ? (float)((const bf16_t*)p)[i] : ((const float*)p)[i];
}

// ---------------- fused level kernel (merged tern+bin): blocks [0,blocks_t) ternary, rest binary
__global__ __launch_bounds__(256, 2) void fused_level(
    const int* __restrict__ list_t, const int* __restrict__ list_b,
    const int* __restrict__ cntpair, const int* __restrict__ lvl_idx,
    const int* __restrict__ op_ids, const int* __restrict__ lch,
    const int* __restrict__ rch, const int* __restrict__ tch,
    bf16_t* __restrict__ ne2, const bf16_t* __restrict__ opb,
    const void* __restrict__ ct, const int* __restrict__ cid,
    const int* __restrict__ inv, const int* __restrict__ flagp,
    const bf16_t* __restrict__ W1tp, const void* __restrict__ b1t,
    const bf16_t* __restrict__ W2tp, const void* __restrict__ b2t,
    const bf16_t* __restrict__ W1bp, const void* __restrict__ b1b,
    const bf16_t* __restrict__ W2bp, const void* __restrict__ b2b,
    const void* __restrict__ gma, const void* __restrict__ bta,
    int slotBase, void* __restrict__ out)
{
    __shared__ __align__(16) unsigned short reg1[20480]; // B1 slab [512][40] | H [32][520] | R float[32][260]
    __shared__ __align__(16) unsigned short regA[1280];  // A chunk [32][40]  | LN partials
    __shared__ __align__(16) unsigned short reg2[10240]; // B2 slab [256][40]

    const int tid = threadIdx.x;
    const int w = tid >> 6, lane = tid & 63, cc = lane & 15, qq = lane >> 4;
    const int cnt_t = cntpair[1], cnt_b = cntpair[0];
    const int blocks_t = (cnt_t + 31) >> 5;
    int tern, base, cnt, K1c;
    const int* list;
    const bf16_t *W1p, *W2p;
    const void *b1, *b2;
    if ((int)blockIdx.x < blocks_t) {
        tern = 1; list = list_t; base = blockIdx.x * 32; cnt = cnt_t;
        W1p = W1tp; b1 = b1t; W2p = W2tp; b2 = b2t; K1c = 32;
    } else {
        tern = 0; list = list_b; base = (blockIdx.x - blocks_t) * 32; cnt = cnt_b;
        if (base >= cnt) return;
        W1p = W1bp; b1 = b1b; W2p = W2bp; b2 = b2b; K1c = 24;
    }
    const int act = min(32, cnt - base);
    const int isbf = *flagp;

    // staging identity: thread covers row ms, col-group gs
    const int ms = tid >> 3, gs = tid & 7;
    const int rowS = list[base + min(ms, act - 1)];
    const int nodeS = lvl_idx[rowS];
    const int opS = op_ids[nodeS];
    const int lS = lch[nodeS], rS = rch[nodeS];
    const int tS = tern ? tch[nodeS] : lS;
    int sInv[3], sCid[3];
    {
        int sn[3] = {lS, rS, tS};
        for (int s = 0; s < 3; s++) {
            sInv[s] = inv[sn[s]];
            sCid[s] = sInv[s] < 0 ? cid[sn[s]] : 0;
        }
    }

    // per-lane bias / gamma / beta (cols owned by this lane)
    float b1f[8];
    for (int j = 0; j < 8; j++) b1f[j] = ldparam(b1, (w + 4 * j) * 16 + cc, isbf);
    float b2f[4], gf[4], btf[4];
    for (int j = 0; j < 4; j++) {
        int col = (w + 4 * j) * 16 + cc;
        b2f[j] = ldparam(b2, col, isbf);
        gf[j] = ldparam(gma, col, isbf);
        btf[j] = ldparam(bta, col, isbf);
    }

    const f32x4 zf = {0.f, 0.f, 0.f, 0.f};
    f32x4 acc1[2][8];
    for (int m = 0; m < 2; m++) for (int j = 0; j < 8; j++) acc1[m][j] = zf;

    // ---------- GEMM1: [32 x K1] @ [K1 x 512]
    for (int kc = 0; kc < K1c; kc++) {
        __syncthreads();
        { // A chunk gather: 32 rows x 32 cols of concat(op,le,re[,te])
            int colg = kc * 32 + gs * 4;
            int piece = colg >> 8, po = colg & 255;
            u16x4 hv;
            if (piece == 0) {
                hv = *(const u16x4*)((const unsigned short*)opb + opS * 256 + po);
            } else {
                int s = piece - 1;
                if (sInv[s] >= 0) {
                    hv = *(const u16x4*)((const unsigned short*)ne2 + (size_t)sInv[s] * 256 + po);
                } else if (isbf) {
                    hv = *(const u16x4*)((const unsigned short*)ct + (size_t)sCid[s] * 256 + po);
                } else {
                    f32x4 fv = *(const f32x4*)((const float*)ct + (size_t)sCid[s] * 256 + po);
                    bf16_t tmp[4];
                    for (int z = 0; z < 4; z++) tmp[z] = (bf16_t)fv[z];
                    hv = *(u16x4*)tmp;
                }
            }
            *(u16x4*)(regA + ms * LBS + gs * 4) = hv;
        }
        // B slab: 512n x 32k shorts = 2048 16B chunks, 8 per thread
        for (int i = 0; i < 8; i++) {
            int idx = i * 256 + tid;
            int n = idx >> 2, g = idx & 3;
            u16x8 v = *(const u16x8*)((const unsigned short*)W1p + ((size_t)kc * 512 + n) * 32 + g * 8);
            *(u16x8*)(reg1 + n * LBS + g * 8) = v;
        }
        __syncthreads();
        bf16x8 af[2];
        for (int m = 0; m < 2; m++)
            af[m] = *(const bf16x8*)((const bf16_t*)regA + (m * 16 + cc) * LBS + qq * 8);
        for (int j = 0; j < 8; j++) {
            bf16x8 bfv = *(const bf16x8*)((const bf16_t*)reg1 + ((w + 4 * j) * 16 + cc) * LBS + qq * 8);
            for (int m = 0; m < 2; m++)
                acc1[m][j] = __builtin_amdgcn_mfma_f32_16x16x32_bf16(af[m], bfv, acc1[m][j], 0, 0, 0);
        }
    }
    __syncthreads();

    // ---------- bias + exact GELU -> H in LDS [32][512] (stride 520)
    {
        bf16_t* Hl = (bf16_t*)reg1;
        for (int m = 0; m < 2; m++) for (int j = 0; j < 8; j++) {
            int col = (w + 4 * j) * 16 + cc;
            for (int r = 0; r < 4; r++) {
                float v = acc1[m][j][r] + b1f[j];
                float h = 0.5f * v * (1.0f + erff(v * 0.70710678118654752f));
                Hl[(m * 16 + qq * 4 + r) * LHS + col] = (bf16_t)h;
            }
        }
    }
    __syncthreads();

    // ---------- GEMM2: [32 x 512] @ [512 x 256]
    f32x4 acc2[2][4];
    for (int m = 0; m < 2; m++) for (int j = 0; j < 4; j++) acc2[m][j] = zf;
    for (int kc = 0; kc < 16; kc++) {
        if (kc) __syncthreads();
        for (int i = 0; i < 4; i++) {
            int idx = i * 256 + tid;
            int n = idx >> 2, g = idx & 3;
            u16x8 v = *(const u16x8*)((const unsigned short*)W2p + ((size_t)kc * 256 + n) * 32 + g * 8);
            *(u16x8*)(reg2 + n * LBS + g * 8) = v;
        }
        __syncthreads();
        bf16x8 af[2];
        for (int m = 0; m < 2; m++)
            af[m] = *(const bf16x8*)((const bf16_t*)reg1 + (m * 16 + cc) * LHS + kc * 32 + qq * 8);
        for (int j = 0; j < 4; j++) {
            bf16x8 bfv = *(const bf16x8*)((const bf16_t*)reg2 + ((w + 4 * j) * 16 + cc) * LBS + qq * 8);
            for (int m = 0; m < 2; m++)
                acc2[m][j] = __builtin_amdgcn_mfma_f32_16x16x32_bf16(af[m], bfv, acc2[m][j], 0, 0, 0);
        }
    }
    __syncthreads();

    // ---------- residual gather -> reg1 as float[32][260]
    {
        float* Rf = (float*)reg1;
        int colb = gs * 32;
        for (int i = 0; i < 4; i++) {
            int q = colb + i * 8;
            float lv[8], rv[8], tv[8];
            load8f(ne2, ct, isbf, sInv[0], sCid[0], q, lv);
            load8f(ne2, ct, isbf, sInv[1], sCid[1], q, rv);
            if (tern) load8f(ne2, ct, isbf, sInv[2], sCid[2], q, tv);
            f32x4 s0, s1;
            if (tern) {
                for (int z = 0; z < 4; z++) {
                    s0[z] = (lv[z] + rv[z] + tv[z]) * (1.0f / 3.0f);
                    s1[z] = (lv[z + 4] + rv[z + 4] + tv[z + 4]) * (1.0f / 3.0f);
                }
            } else {
                for (int z = 0; z < 4; z++) {
                    s0[z] = lv[z] + rv[z];
                    s1[z] = lv[z + 4] + rv[z + 4];
                }
            }
            *(f32x4*)(Rf + ms * 260 + q) = s0;
            *(f32x4*)(Rf + ms * 260 + q + 4) = s1;
        }
    }
    __syncthreads();

    // ---------- x = gemm2 + b2 + R ; LayerNorm over 256 cols per row
    float* partS = (float*)regA;      // [4][32]
    float* partQ = partS + 128;       // [4][32]
    float* muA   = partQ + 128;       // [32]
    float* rsA   = muA + 32;          // [32]
    const float* Rf = (const float*)reg1;

    for (int m = 0; m < 2; m++) for (int r = 0; r < 4; r++) {
        int row = m * 16 + qq * 4 + r;
        float ps = 0.f, pq = 0.f;
        for (int j = 0; j < 4; j++) {
            int col = (w + 4 * j) * 16 + cc;
            float x = acc2[m][j][r] + b2f[j] + Rf[row * 260 + col];
            acc2[m][j][r] = x;
            ps += x; pq += x * x;
        }
        for (int d = 1; d < 16; d <<= 1) {
            ps += __shfl_xor(ps, d, 64);
            pq += __shfl_xor(pq, d, 64);
        }
        if (cc == 0) { partS[w * 32 + row] = ps; partQ[w * 32 + row] = pq; }
    }
    __syncthreads();
    if (tid < 32) {
        float s  = partS[tid] + partS[32 + tid] + partS[64 + tid] + partS[96 + tid];
        float sq = partQ[tid] + partQ[32 + tid] + partQ[64 + tid] + partQ[96 + tid];
        float mu = s * (1.0f / 256.0f);
        float var = sq * (1.0f / 256.0f) - mu * mu;
        muA[tid] = mu;
        rsA[tid] = rsqrtf(fmaxf(var, 0.0f) + 1e-5f);
    }
    __syncthreads();

    for (int m = 0; m < 2; m++) for (int r = 0; r < 4; r++) {
        int row = m * 16 + qq * 4 + r;
        if (row >= act) continue;
        float mu = muA[row], rs = rsA[row];
        int lr2 = list[base + row];
        for (int j = 0; j < 4; j++) {
            int col = (w + 4 * j) * 16 + cc;
            float y = (acc2[m][j][r] - mu) * rs * gf[j] + btf[j];
            if (out) {
                if (isbf) ((bf16_t*)out)[(size_t)lr2 * 256 + col] = (bf16_t)y;
                else      ((float*)out)[(size_t)lr2 * 256 + col] = y;
            } else {
                ne2[(size_t)(slotBase + lr2) * 256 + col] = (bf16_t)y;
            }
        }
    }
}

extern "C" void kernel_launch(void* const* d_in, const int* in_sizes, int n_in,
                              void* d_out, int out_size, void* d_ws, size_t ws_size,
                              hipStream_t stream) {
    const int* cid    = (const int*)d_in[0];
    const int* opids  = (const int*)d_in[1];
    const int* lch    = (const int*)d_in[2];
    const int* rch    = (const int*)d_in[3];
    const int* tch    = (const int*)d_in[4];
    const int* lvl2   = (const int*)d_in[5];
    const int* lvl1   = (const int*)d_in[6];
    const int* lvl0   = (const int*)d_in[7];
    const void* comp_table = d_in[8];
    const void* op_table   = d_in[9];
    const void* W1b = d_in[10];
    const void* b1b = d_in[11];
    const void* W2b = d_in[12];
    const void* b2b = d_in[13];
    const void* W1t = d_in[14];
    const void* b1t = d_in[15];
    const void* W2t = d_in[16];
    const void* b2t = d_in[17];
    const void* gma = d_in[18];
    const void* bta = d_in[19];

    char* wsp = (char*)d_ws;
    bf16_t* ne2  = (bf16_t*)wsp;                 size_t off = 12582912; // 24576*256*2
    bf16_t* opb  = (bf16_t*)(wsp + off);         off += 8192;           // 16*256*2
    bf16_t* W1bp = (bf16_t*)(wsp + off);         off += 786432;         // 768*512*2
    bf16_t* W1tp = (bf16_t*)(wsp + off);         off += 1048576;        // 1024*512*2
    bf16_t* W2bp = (bf16_t*)(wsp + off);         off += 262144;         // 512*256*2
    bf16_t* W2tp = (bf16_t*)(wsp + off);         off += 262144;
    int* inv   = (int*)(wsp + off);              off += 262144;         // 65536*4
    int* lists = (int*)(wsp + off);              off += 229376;         // 57344*4
    int* cnts  = (int*)(wsp + off);              off += 64;             // total ~15.4 MB
    int* flag  = cnts + 8;

    hipMemsetAsync(cnts, 0, 64, stream);
    hipMemsetAsync(inv, 0xFF, 262144, stream);
    detect_dtype<<<1, 64, 0, stream>>>((const unsigned short*)comp_table, flag);
    scan_rows<<<112, 256, 0, stream>>>(lvl2, lvl1, lvl0, tch, lists, cnts, inv);
    conv_op<<<16, 256, 0, stream>>>(op_table, opb, flag);
    pack_w<<<1536, 256, 0, stream>>>(W1b, W1bp, 393216, 511, 9, flag);
    pack_w<<<2048, 256, 0, stream>>>(W1t, W1tp, 524288, 511, 9, flag);
    pack_w<<<512, 256, 0, stream>>>(W2b, W2bp, 131072, 255, 8, flag);
    pack_w<<<512, 256, 0, stream>>>(W2t, W2tp, 131072, 255, 8, flag);

    // level 2: lists t @0 / b @16384, cnts slot 0 -> slots base 0
    fused_level<<<513, 256, 0, stream>>>(lists + 0, lists + 16384, cnts + 0, lvl2,
        opids, lch, rch, tch, ne2, opb, comp_table, cid, inv, flag,
        W1tp, b1t, W2tp, b2t, W1bp, b1b, W2bp, b2b, gma, bta, 0, nullptr);
    // level 1: lists t @32768 / b @40960, cnts slot 1 -> slots base 16384
    fused_level<<<257, 256, 0, stream>>>(lists + 32768, lists + 40960, cnts + 2, lvl1,
        opids, lch, rch, tch, ne2, opb, comp_table, cid, inv, flag,
        W1tp, b1t, W2tp, b2t, W1bp, b1b, W2bp, b2b, gma, bta, 16384, nullptr);
    // level 0: lists t @49152 / b @53248, cnts slot 2 -> d_out
    fused_level<<<129, 256, 0, stream>>>(lists + 49152, lists + 53248, cnts + 4, lvl0,
        opids, lch, rch, tch, ne2, opb, comp_table, cid, inv, flag,
        W1tp, b1t, W2tp, b2t, W1bp, b1b, W2bp, b2b, gma, bta, 0, d_out);
}